// Round 4
// baseline (223.155 us; speedup 1.0000x reference)
//
#include <hip/hip_runtime.h>

typedef unsigned short ushort_t;
typedef __bf16 bf16x8 __attribute__((ext_vector_type(8)));
typedef float f32x4 __attribute__((ext_vector_type(4)));
typedef float f32x2 __attribute__((ext_vector_type(2)));
typedef ushort_t us4 __attribute__((ext_vector_type(4)));

#define T_SOFT 32.0f
#define THRESH 0.76604444311897803f   // cos(40 deg)

__device__ __forceinline__ ushort_t f2bf(float f) {
  union { float f; unsigned u; } x; x.f = f;
  unsigned r = (x.u + 0x7fffu + ((x.u >> 16) & 1u)) >> 16;  // RNE
  return (ushort_t)r;
}

// pack 4 fp32 -> 4 bf16 (round-half-up via +0x8000 + byte perm)
__device__ __forceinline__ us4 pack4(float4 x) {
  union { unsigned u[2]; us4 h; } r;
  union { float4 f; unsigned u[4]; } a;
  a.f = x;
  r.u[0] = __builtin_amdgcn_perm(a.u[1] + 0x8000u, a.u[0] + 0x8000u, 0x07060302u);
  r.u[1] = __builtin_amdgcn_perm(a.u[3] + 0x8000u, a.u[2] + 0x8000u, 0x07060302u);
  return r.h;
}

// ---------------- tr3 + zero-init: transposes, plus zero img_h / proto_red / gn_bf tail ----------------
__global__ __launch_bounds__(256) void tr3_k(const float* __restrict__ s0, ushort_t* __restrict__ d0,
                                             const float* __restrict__ s1, ushort_t* __restrict__ d1,
                                             const float* __restrict__ s2, ushort_t* __restrict__ d2,
                                             float* __restrict__ z0, float* __restrict__ z1,
                                             ushort_t* __restrict__ gn_bf) {
  int b = blockIdx.x, tid = threadIdx.x;
  if (b >= 976) {
    if (b < 1040) {           // zero img_h: 65536 float4
      int local = b - 976;
      float4 z = make_float4(0.f, 0.f, 0.f, 0.f);
      float4* p = reinterpret_cast<float4*>(z0) + local * 1024 + tid;
      p[0] = z; p[256] = z; p[512] = z; p[768] = z;
    } else if (b < 1117) {    // zero proto_red: 78000 float4
      int local = b - 1040;
      float4 z = make_float4(0.f, 0.f, 0.f, 0.f);
      float4* p = reinterpret_cast<float4*>(z1);
      int base = local * 1024 + tid;
      #pragma unroll
      for (int i = 0; i < 4; ++i) { int idx = base + i * 256; if (idx < 78000) p[idx] = z; }
    } else {                  // zero gn_bf rows 1000-1007 (1024 bf16)
      us4 z = {0, 0, 0, 0};
      *reinterpret_cast<us4*>(gn_bf + 1000 * 128 + tid * 4) = z;
    }
    return;
  }
  __shared__ float tl[32][33];
  const float* src; ushort_t* dst; int R, C, Rpad, local, ctiles;
  if (b < 640)      { src = s0; dst = d0; R = 2048; C = 312; Rpad = 2048; local = b;       ctiles = 10; }
  else if (b < 896) { src = s1; dst = d1; R = 2048; C = 128; Rpad = 2048; local = b - 640; ctiles = 4;  }
  else              { src = s2; dst = d2; R = 624;  C = 128; Rpad = 640;  local = b - 896; ctiles = 4;  }
  int rt = local / ctiles, ct = local - rt * ctiles;
  int r0 = rt * 32, c0 = ct * 32;
  #pragma unroll
  for (int p = 0; p < 4; ++p) {
    int idx = p * 256 + tid;
    int rr = idx >> 5, cc = idx & 31;
    float v = 0.f;
    if (r0 + rr < R && c0 + cc < C) v = src[(size_t)(r0 + rr) * C + (c0 + cc)];
    tl[cc][rr] = v;
  }
  __syncthreads();
  int cc = tid >> 3, rq = tid & 7;
  if (c0 + cc < C) {
    us4 o;
    o[0] = f2bf(tl[cc][rq * 4 + 0]);
    o[1] = f2bf(tl[cc][rq * 4 + 1]);
    o[2] = f2bf(tl[cc][rq * 4 + 2]);
    o[3] = f2bf(tl[cc][rq * 4 + 3]);
    *reinterpret_cast<us4*>(dst + (size_t)(c0 + cc) * Rpad + r0 + rq * 4) = o;
  }
}

// ---------------- LDS-staged split-K GEMM segment ----------------
// block: 256 thr, tile 128 rows x (16*NCT) cols, BK=64, atomicAdd epilogue
// A fp32 [M,lda] (rows clamped), BT bf16 [*,ldbt] (row = col of C), C fp32 [M,N]
template <int NCT>
__device__ __forceinline__ void gemm_seg(
    const float* __restrict__ A, int M, int lda,
    const ushort_t* __restrict__ BT, int ldbt,
    float* __restrict__ C, int N,
    int r0, int c0, int k0, int nsteps,
    ushort_t* __restrict__ As, ushort_t* __restrict__ Bs, int tid) {
  const int SA = 72;                 // LDS row stride in bf16
  const int BP = NCT / 2;            // B staging passes (rows = NCT*16, 32/pass)
  int lane = tid & 63, wv = tid >> 6;
  int l15 = lane & 15, quad = lane >> 4;
  int arow = tid >> 4, akq = tid & 15;   // A stage: 16 rows/pass x 16 float4 lanes
  int brow = tid >> 3, bkq = tid & 7;    // B stage: 32 rows/pass x 8 b128 lanes

  const float* agp[8];
  #pragma unroll
  for (int p = 0; p < 8; ++p) {
    int r = r0 + arow + p * 16; if (r >= M) r = M - 1;
    agp[p] = A + (size_t)r * lda + k0 + akq * 4;
  }
  const ushort_t* bgp[BP];
  #pragma unroll
  for (int p = 0; p < BP; ++p)
    bgp[p] = BT + (size_t)(c0 + brow + p * 32) * ldbt + k0 + bkq * 8;

  float4 ap[8]; bf16x8 bp[BP];
  #pragma unroll
  for (int p = 0; p < 8; ++p) ap[p] = *reinterpret_cast<const float4*>(agp[p]);
  #pragma unroll
  for (int p = 0; p < BP; ++p) bp[p] = *reinterpret_cast<const bf16x8*>(bgp[p]);

  f32x4 acc[2][NCT];
  #pragma unroll
  for (int i = 0; i < 2; ++i)
    #pragma unroll
    for (int j = 0; j < NCT; ++j) acc[i][j] = f32x4{0.f, 0.f, 0.f, 0.f};

  for (int s = 0; s < nsteps; ++s) {
    if (s) __syncthreads();
    // stage regs -> LDS (compiler inserts fine-grained vmcnt waits)
    #pragma unroll
    for (int p = 0; p < 8; ++p)
      *reinterpret_cast<us4*>(As + (arow + p * 16) * SA + akq * 4) = pack4(ap[p]);
    #pragma unroll
    for (int p = 0; p < BP; ++p)
      *reinterpret_cast<bf16x8*>(Bs + (brow + p * 32) * SA + bkq * 8) = bp[p];
    // prefetch next step while MFMA runs
    if (s + 1 < nsteps) {
      #pragma unroll
      for (int p = 0; p < 8; ++p) ap[p] = *reinterpret_cast<const float4*>(agp[p] + 64);
      #pragma unroll
      for (int p = 0; p < BP; ++p) bp[p] = *reinterpret_cast<const bf16x8*>(bgp[p] + 64);
      #pragma unroll
      for (int p = 0; p < 8; ++p) agp[p] += 64;
      #pragma unroll
      for (int p = 0; p < BP; ++p) bgp[p] += 64;
    }
    __syncthreads();
    #pragma unroll
    for (int kh = 0; kh < 2; ++kh) {
      bf16x8 af[2];
      #pragma unroll
      for (int pi = 0; pi < 2; ++pi)
        af[pi] = *reinterpret_cast<bf16x8*>(As + ((wv * 2 + pi) * 16 + l15) * SA + kh * 32 + quad * 8);
      #pragma unroll
      for (int ct = 0; ct < NCT; ++ct) {
        bf16x8 bf = *reinterpret_cast<bf16x8*>(Bs + (ct * 16 + l15) * SA + kh * 32 + quad * 8);
        acc[0][ct] = __builtin_amdgcn_mfma_f32_16x16x32_bf16(af[0], bf, acc[0][ct], 0, 0, 0);
        acc[1][ct] = __builtin_amdgcn_mfma_f32_16x16x32_bf16(af[1], bf, acc[1][ct], 0, 0, 0);
      }
    }
  }
  #pragma unroll
  for (int pi = 0; pi < 2; ++pi) {
    #pragma unroll
    for (int ct = 0; ct < NCT; ++ct) {
      int col = c0 + ct * 16 + l15;
      if (col < N) {
        #pragma unroll
        for (int r = 0; r < 4; ++r) {
          int row = r0 + (wv * 2 + pi) * 16 + quad * 4 + r;
          if (row < M) atomicAdd(&C[(size_t)row * N + col], acc[pi][ct][r]);
        }
      }
    }
  }
}

// ---------------- mega: gn (125) + img_h GEMM (64) + proto_red GEMM (96) ----------------
__global__ __launch_bounds__(256) void mega_k(
    const float* __restrict__ attributes, const float* __restrict__ att_g,
    ushort_t* __restrict__ gn_bf,
    const float* __restrict__ img_proto, const ushort_t* __restrict__ slimT,
    float* __restrict__ proto_red,
    const float* __restrict__ image_feats, const ushort_t* __restrict__ imgwT,
    float* __restrict__ img_h) {
  __shared__ ushort_t As[128 * 72];
  __shared__ ushort_t Bs[128 * 72];
  int b = blockIdx.x, tid = threadIdx.x;
  if (b < 125) {
    __shared__ float a_lds[8][316];
    __shared__ float red2[8][2];
    int h = tid & 127;
    int c0 = b * 8;
    for (int idx = tid; idx < 8 * 312; idx += 256) {
      int r = idx / 312;
      int k = idx - r * 312;
      a_lds[r][k] = attributes[(c0 + r) * 312 + k];
    }
    __syncthreads();
    float acc[8] = {0.f,0.f,0.f,0.f,0.f,0.f,0.f,0.f};
    for (int k = 0; k < 312; k += 4) {
      float w0 = att_g[(k + 0) * 128 + h];
      float w1 = att_g[(k + 1) * 128 + h];
      float w2 = att_g[(k + 2) * 128 + h];
      float w3 = att_g[(k + 3) * 128 + h];
      #pragma unroll
      for (int r = 0; r < 8; ++r) {
        float4 a4 = *reinterpret_cast<const float4*>(&a_lds[r][k]);
        acc[r] += a4.x * w0 + a4.y * w1 + a4.z * w2 + a4.w * w3;
      }
    }
    int lane = tid & 63, wvid = (tid >> 6) & 1;
    #pragma unroll
    for (int r = 0; r < 8; ++r) {
      float v = acc[r] * acc[r];
      #pragma unroll
      for (int off = 32; off > 0; off >>= 1) v += __shfl_xor(v, off, 64);
      if (lane == 0) red2[r][wvid] = v;   // duplicate waves write identical values
    }
    __syncthreads();
    #pragma unroll
    for (int r = 0; r < 8; ++r) {
      float nrm = fmaxf(sqrtf(red2[r][0] + red2[r][1]), 1e-12f);
      gn_bf[(c0 + r) * 128 + h] = f2bf(acc[r] / nrm);
    }
    return;
  }
  b -= 125;
  if (b < 64) {            // img_h: 16 row-blocks x 4 K-chunks, N=128
    int rb = b >> 2, kc = b & 3;
    gemm_seg<8>(image_feats, 2048, 2048, imgwT, 2048, img_h, 128,
                rb * 128, 0, kc * 512, 8, As, Bs, tid);
  } else {                 // proto_red: 8 row-blocks x 3 col-blocks x 4 K-chunks, N=312
    b -= 64;
    int kc = b & 3; int t = b >> 2;
    int rb = t / 3, cb = t - rb * 3;
    if (cb == 2)
      gemm_seg<4>(img_proto, 1000, 2048, slimT, 2048, proto_red, 312,
                  rb * 128, 256, kc * 512, 8, As, Bs, tid);
    else
      gemm_seg<8>(img_proto, 1000, 2048, slimT, 2048, proto_red, 312,
                  rb * 128, cb * 128, kc * 512, 8, As, Bs, tid);
  }
}

// ---------------- attn v2: MFMA sim on bf16 gn + sparse gather ----------------
// grid 63 blocks (16 i-rows each), 256 thr
__global__ __launch_bounds__(256) void attn2_k(
    const ushort_t* __restrict__ gn_bf, const float* __restrict__ attributes,
    const float* __restrict__ proto_red, const float* __restrict__ slim_b,
    ushort_t* __restrict__ outs) {
  __shared__ int cnt;
  __shared__ int ij[256];
  __shared__ float wl[256];
  int tid = threadIdx.x;
  int i0 = blockIdx.x * 16;
  if (tid == 0) cnt = 0;
  __syncthreads();
  int lane = tid & 63, wv = tid >> 6;
  int l15 = lane & 15, quad = lane >> 4;
  const ushort_t* abase = gn_bf + (size_t)(i0 + l15) * 128 + quad * 8;
  bf16x8 af0 = *reinterpret_cast<const bf16x8*>(abase);
  bf16x8 af1 = *reinterpret_cast<const bf16x8*>(abase + 32);
  bf16x8 af2 = *reinterpret_cast<const bf16x8*>(abase + 64);
  bf16x8 af3 = *reinterpret_cast<const bf16x8*>(abase + 96);
  for (int jt = wv; jt < 63; jt += 4) {
    const ushort_t* bbase = gn_bf + (size_t)(jt * 16 + l15) * 128 + quad * 8;
    f32x4 d = {0.f, 0.f, 0.f, 0.f};
    d = __builtin_amdgcn_mfma_f32_16x16x32_bf16(af0, *reinterpret_cast<const bf16x8*>(bbase),      d, 0, 0, 0);
    d = __builtin_amdgcn_mfma_f32_16x16x32_bf16(af1, *reinterpret_cast<const bf16x8*>(bbase + 32), d, 0, 0, 0);
    d = __builtin_amdgcn_mfma_f32_16x16x32_bf16(af2, *reinterpret_cast<const bf16x8*>(bbase + 64), d, 0, 0, 0);
    d = __builtin_amdgcn_mfma_f32_16x16x32_bf16(af3, *reinterpret_cast<const bf16x8*>(bbase + 96), d, 0, 0, 0);
    int j = jt * 16 + l15;
    #pragma unroll
    for (int r = 0; r < 4; ++r) {
      if (d[r] > THRESH) {
        int p = atomicAdd(&cnt, 1);
        if (p < 256) { ij[p] = ((quad * 4 + r) << 16) | j; wl[p] = __expf(T_SOFT * d[r]); }
      }
    }
  }
  __syncthreads();
  int n = cnt < 256 ? cnt : 256;
  for (int idx = tid; idx < 16 * 640; idx += 256) {
    int il = idx / 640, c = idx - il * 640;
    int gi = i0 + il;
    if (gi >= 1000) continue;
    ushort_t res = 0;
    if (c < 624) {
      float sw = 0.f, sv = 0.f;
      for (int t = 0; t < n; ++t) {
        int e = ij[t];
        if ((e >> 16) == il) {
          int j = e & 0xffff;
          float w = wl[t];
          float v = (c < 312) ? attributes[(size_t)j * 312 + c]
                              : proto_red[(size_t)j * 312 + (c - 312)];
          sw += w; sv += w * v;
        }
      }
      float r = sv / sw;
      if (c >= 312) r += slim_b[c - 312];
      res = f2bf(r);
    }
    outs[(size_t)gi * 640 + c] = res;   // cols 624-639 zeroed (K-pad)
  }
}

// ---------------- bf16 MFMA GEMM (ph = outs @ proto_w + proto_b) ----------------
__global__ __launch_bounds__(256) void mfma_gemm_bt(
    const ushort_t* __restrict__ A, const ushort_t* __restrict__ BT,
    float* __restrict__ C, int M, int N, int K, int Mt, int Nt,
    const float* __restrict__ bias) {
  int wid = blockIdx.x * 4 + (threadIdx.x >> 6);
  int lane = threadIdx.x & 63;
  int tm = wid / Nt;
  int tn = wid - tm * Nt;
  if (tm >= Mt) return;
  int l15 = lane & 15;
  int quad = lane >> 4;
  const bf16x8* ap = reinterpret_cast<const bf16x8*>(A + (size_t)(tm * 16 + l15) * K + quad * 8);
  const bf16x8* bp = reinterpret_cast<const bf16x8*>(BT + (size_t)(tn * 16 + l15) * K + quad * 8);
  f32x4 acc = {0.f, 0.f, 0.f, 0.f};
  for (int s = 0, steps = K >> 7; s < steps; ++s) {
    bf16x8 a0 = ap[0],  b0 = bp[0];
    bf16x8 a1 = ap[4],  b1 = bp[4];
    bf16x8 a2 = ap[8],  b2 = bp[8];
    bf16x8 a3 = ap[12], b3 = bp[12];
    ap += 16; bp += 16;
    acc = __builtin_amdgcn_mfma_f32_16x16x32_bf16(a0, b0, acc, 0, 0, 0);
    acc = __builtin_amdgcn_mfma_f32_16x16x32_bf16(a1, b1, acc, 0, 0, 0);
    acc = __builtin_amdgcn_mfma_f32_16x16x32_bf16(a2, b2, acc, 0, 0, 0);
    acc = __builtin_amdgcn_mfma_f32_16x16x32_bf16(a3, b3, acc, 0, 0, 0);
  }
  int col = tn * 16 + l15;
  if (col >= N) return;
  float bv = bias ? bias[col] : 0.f;
  int row0 = tm * 16 + quad * 4;
  #pragma unroll
  for (int r = 0; r < 4; ++r) {
    int row = row0 + r;
    if (row < M) C[(size_t)row * N + col] = acc[r] + bv;
  }
}

// ---------------- final: out[b,c] = fc_b + sum_h relu(img_h[b,h]+ph[c,h]) * fc_w[h] ----------------
__global__ __launch_bounds__(256) void final_k(
    const float* __restrict__ img_h, const float* __restrict__ ph,
    const float* __restrict__ fc_w, const float* __restrict__ fc_b,
    float* __restrict__ out) {
  __shared__ float ih[128][132];
  __shared__ float ps[64][132];
  __shared__ float ws_[128];
  int tid = threadIdx.x;
  int b0 = blockIdx.x * 128;
  int c0 = blockIdx.y * 64;
  for (int idx = tid; idx < 4096; idx += 256) {
    int row = idx >> 5, c4 = (idx & 31) * 4;
    float4 v = *reinterpret_cast<const float4*>(img_h + (size_t)(b0 + row) * 128 + c4);
    *reinterpret_cast<float4*>(&ih[row][c4]) = v;
  }
  for (int idx = tid; idx < 2048; idx += 256) {
    int row = idx >> 5, c4 = (idx & 31) * 4;
    int c = c0 + row;
    float4 v = make_float4(0.f, 0.f, 0.f, 0.f);
    if (c < 1000) v = *reinterpret_cast<const float4*>(ph + (size_t)c * 128 + c4);
    *reinterpret_cast<float4*>(&ps[row][c4]) = v;
  }
  if (tid < 128) ws_[tid] = fc_w[tid];
  __syncthreads();
  int tx = tid & 15, ty = tid >> 4;
  f32x2 acc[8][4] = {};
  const f32x2 zero2 = {0.f, 0.f};
  for (int h = 0; h < 128; h += 4) {
    float4 w4 = *reinterpret_cast<float4*>(&ws_[h]);
    f32x2 wlo = {w4.x, w4.y}, whi = {w4.z, w4.w};
    float4 a4[8], p4[4];
    #pragma unroll
    for (int i = 0; i < 8; ++i) a4[i] = *reinterpret_cast<float4*>(&ih[ty * 8 + i][h]);
    #pragma unroll
    for (int j = 0; j < 4; ++j) p4[j] = *reinterpret_cast<float4*>(&ps[tx * 4 + j][h]);
    #pragma unroll
    for (int i = 0; i < 8; ++i) {
      f32x2 alo = {a4[i].x, a4[i].y}, ahi = {a4[i].z, a4[i].w};
      #pragma unroll
      for (int j = 0; j < 4; ++j) {
        f32x2 plo = {p4[j].x, p4[j].y}, phi = {p4[j].z, p4[j].w};
        f32x2 t0 = __builtin_elementwise_max(alo + plo, zero2);
        f32x2 t1 = __builtin_elementwise_max(ahi + phi, zero2);
        acc[i][j] = acc[i][j] + t0 * wlo;
        acc[i][j] = acc[i][j] + t1 * whi;
      }
    }
  }
  float fb = fc_b[0];
  #pragma unroll
  for (int i = 0; i < 8; ++i) {
    int b = b0 + ty * 8 + i;
    int c = c0 + tx * 4;
    if (c < 1000) {
      float4 v = make_float4(acc[i][0].x + acc[i][0].y + fb, acc[i][1].x + acc[i][1].y + fb,
                             acc[i][2].x + acc[i][2].y + fb, acc[i][3].x + acc[i][3].y + fb);
      *reinterpret_cast<float4*>(out + (size_t)b * 1000 + c) = v;
    }
  }
}

extern "C" void kernel_launch(void* const* d_in, const int* in_sizes, int n_in,
                              void* d_out, int out_size, void* d_ws, size_t ws_size,
                              hipStream_t stream) {
  const float* image_feats = (const float*)d_in[0];   // [2048,2048]
  const float* img_proto   = (const float*)d_in[1];   // [1000,2048]
  const float* attributes  = (const float*)d_in[2];   // [1000,312]
  const float* att_g   = (const float*)d_in[4];       // [312,128]
  const float* slim_w  = (const float*)d_in[5];       // [2048,312]
  const float* slim_b  = (const float*)d_in[6];       // [312]
  const float* img_w   = (const float*)d_in[7];       // [2048,128]
  const float* proto_w = (const float*)d_in[8];       // [624,128]
  const float* proto_b = (const float*)d_in[9];       // [1,128]
  const float* fc_w    = (const float*)d_in[10];      // [128,1]
  const float* fc_b    = (const float*)d_in[11];      // [1]
  float* out = (float*)d_out;                         // [2048,1000]

  char* ws = (char*)d_ws;
  size_t o = 0;
  auto alloc = [&](size_t bytes) { size_t r = o; o += (bytes + 255) & ~(size_t)255; return r; };
  ushort_t* imgwT   = (ushort_t*)(ws + alloc(128ull * 2048 * 2));   // img_w^T bf16
  ushort_t* slimT   = (ushort_t*)(ws + alloc(320ull * 2048 * 2));   // slim_w^T bf16 (rows 312-319 junk)
  ushort_t* protowT = (ushort_t*)(ws + alloc(128ull * 640 * 2));    // proto_w^T bf16, K-pad zeros
  ushort_t* gn_bf   = (ushort_t*)(ws + alloc(1008ull * 128 * 2));   // normalized g, bf16, rows 1000-1007 zero
  float* proto_red = (float*)(ws + alloc(1000ull * 312 * 4));       // atomic target (zero-init, NO bias)
  ushort_t* outs_bf = (ushort_t*)(ws + alloc(1008ull * 640 * 2));   // concat outs bf16
  float* img_h     = (float*)(ws + alloc(2048ull * 128 * 4));       // atomic target (zero-init)
  float* ph        = (float*)(ws + alloc(1000ull * 128 * 4));

  // transposes (976) + zero img_h (64) + zero proto_red (77) + gn_bf tail (1)
  tr3_k<<<1118, 256, 0, stream>>>(slim_w, slimT, img_w, imgwT, proto_w, protowT,
                                  img_h, proto_red, gn_bf);

  // gn (125) + img_h GEMM (64) + proto_red GEMM (96)
  mega_k<<<285, 256, 0, stream>>>(attributes, att_g, gn_bf,
                                  img_proto, slimT, proto_red,
                                  image_feats, imgwT, img_h);

  attn2_k<<<63, 256, 0, stream>>>(gn_bf, attributes, proto_red, slim_b, outs_bf);

  // ph = outs @ proto_w + proto_b   (M=1000,N=128,K=640)
  mfma_gemm_bt<<<126, 256, 0, stream>>>(outs_bf, protowT, ph, 1000, 128, 640, 63, 8, proto_b);

  final_k<<<dim3(16, 16), 256, 0, stream>>>(img_h, ph, fc_w, fc_b, out);
}

// Round 5
// 182.716 us; speedup vs baseline: 1.2213x; 1.2213x over previous
//
#include <hip/hip_runtime.h>

typedef unsigned short ushort_t;
typedef __bf16 bf16x8 __attribute__((ext_vector_type(8)));
typedef float f32x4 __attribute__((ext_vector_type(4)));
typedef float f32x2 __attribute__((ext_vector_type(2)));
typedef ushort_t us4 __attribute__((ext_vector_type(4)));

#define T_SOFT 32.0f
#define THRESH 0.76604444311897803f   // cos(40 deg)
#define SW 1048                       // W_lds row stride (bf16): 16B-aligned, 2-way-free banks

__device__ __forceinline__ ushort_t f2bf(float f) {
  union { float f; unsigned u; } x; x.f = f;
  unsigned r = (x.u + 0x7fffu + ((x.u >> 16) & 1u)) >> 16;  // RNE
  return (ushort_t)r;
}
__device__ __forceinline__ float bf2f(ushort_t h) {
  union { unsigned u; float f; } x; x.u = ((unsigned)h) << 16; return x.f;
}

// pack 4 fp32 -> 4 bf16 (round-half-up via +0x8000 + byte perm)
__device__ __forceinline__ us4 pack4(float4 x) {
  union { unsigned u[2]; us4 h; } r;
  union { float4 f; unsigned u[4]; } a;
  a.f = x;
  r.u[0] = __builtin_amdgcn_perm(a.u[1] + 0x8000u, a.u[0] + 0x8000u, 0x07060302u);
  r.u[1] = __builtin_amdgcn_perm(a.u[3] + 0x8000u, a.u[2] + 0x8000u, 0x07060302u);
  return r.h;
}

// ---------------- tr3: transposes + attrT + zero-inits ----------------
__global__ __launch_bounds__(256) void tr3_k(const float* __restrict__ s0, ushort_t* __restrict__ d0,
                                             const float* __restrict__ s1, ushort_t* __restrict__ d1,
                                             const float* __restrict__ s2, ushort_t* __restrict__ d2,
                                             const float* __restrict__ s3, ushort_t* __restrict__ d3,
                                             float* __restrict__ z0, float* __restrict__ z1,
                                             ushort_t* __restrict__ gn_bf) {
  int b = blockIdx.x, tid = threadIdx.x;
  if (b >= 1296) {
    if (b < 1360) {           // zero img_h: 65536 float4
      int local = b - 1296;
      float4 z = make_float4(0.f, 0.f, 0.f, 0.f);
      float4* p = reinterpret_cast<float4*>(z0) + local * 1024 + tid;
      p[0] = z; p[256] = z; p[512] = z; p[768] = z;
    } else if (b < 1437) {    // zero proto_red: 78000 float4
      int local = b - 1360;
      float4 z = make_float4(0.f, 0.f, 0.f, 0.f);
      float4* p = reinterpret_cast<float4*>(z1);
      int base = local * 1024 + tid;
      #pragma unroll
      for (int i = 0; i < 4; ++i) { int idx = base + i * 256; if (idx < 78000) p[idx] = z; }
    } else {                  // zero gn_bf rows 1000-1007
      us4 z = {0, 0, 0, 0};
      *reinterpret_cast<us4*>(gn_bf + 1000 * 128 + tid * 4) = z;
    }
    return;
  }
  __shared__ float tl[32][33];
  const float* src; ushort_t* dst; int R, C, Rpad, local, ctiles;
  if (b < 640)       { src = s0; dst = d0; R = 2048; C = 312; Rpad = 2048; local = b;        ctiles = 10; }
  else if (b < 896)  { src = s1; dst = d1; R = 2048; C = 128; Rpad = 2048; local = b - 640;  ctiles = 4;  }
  else if (b < 976)  { src = s2; dst = d2; R = 624;  C = 128; Rpad = 640;  local = b - 896;  ctiles = 4;  }
  else               { src = s3; dst = d3; R = 1000; C = 312; Rpad = 1024; local = b - 976;  ctiles = 10; }
  int rt = local / ctiles, ct = local - rt * ctiles;
  int r0 = rt * 32, c0 = ct * 32;
  #pragma unroll
  for (int p = 0; p < 4; ++p) {
    int idx = p * 256 + tid;
    int rr = idx >> 5, cc = idx & 31;
    float v = 0.f;
    if (r0 + rr < R && c0 + cc < C) v = src[(size_t)(r0 + rr) * C + (c0 + cc)];
    tl[cc][rr] = v;
  }
  __syncthreads();
  int cc = tid >> 3, rq = tid & 7;
  if (c0 + cc < C) {
    us4 o;
    o[0] = f2bf(tl[cc][rq * 4 + 0]);
    o[1] = f2bf(tl[cc][rq * 4 + 1]);
    o[2] = f2bf(tl[cc][rq * 4 + 2]);
    o[3] = f2bf(tl[cc][rq * 4 + 3]);
    *reinterpret_cast<us4*>(dst + (size_t)(c0 + cc) * Rpad + r0 + rq * 4) = o;
  }
}

// ---------------- LDS-staged split-K GEMM segment (unchanged from R4) ----------------
template <int NCT>
__device__ __forceinline__ void gemm_seg(
    const float* __restrict__ A, int M, int lda,
    const ushort_t* __restrict__ BT, int ldbt,
    float* __restrict__ C, int N,
    int r0, int c0, int k0, int nsteps,
    ushort_t* __restrict__ As, ushort_t* __restrict__ Bs, int tid) {
  const int SA = 72;
  const int BP = NCT / 2;
  int lane = tid & 63, wv = tid >> 6;
  int l15 = lane & 15, quad = lane >> 4;
  int arow = tid >> 4, akq = tid & 15;
  int brow = tid >> 3, bkq = tid & 7;

  const float* agp[8];
  #pragma unroll
  for (int p = 0; p < 8; ++p) {
    int r = r0 + arow + p * 16; if (r >= M) r = M - 1;
    agp[p] = A + (size_t)r * lda + k0 + akq * 4;
  }
  const ushort_t* bgp[BP];
  #pragma unroll
  for (int p = 0; p < BP; ++p)
    bgp[p] = BT + (size_t)(c0 + brow + p * 32) * ldbt + k0 + bkq * 8;

  float4 ap[8]; bf16x8 bp[BP];
  #pragma unroll
  for (int p = 0; p < 8; ++p) ap[p] = *reinterpret_cast<const float4*>(agp[p]);
  #pragma unroll
  for (int p = 0; p < BP; ++p) bp[p] = *reinterpret_cast<const bf16x8*>(bgp[p]);

  f32x4 acc[2][NCT];
  #pragma unroll
  for (int i = 0; i < 2; ++i)
    #pragma unroll
    for (int j = 0; j < NCT; ++j) acc[i][j] = f32x4{0.f, 0.f, 0.f, 0.f};

  for (int s = 0; s < nsteps; ++s) {
    if (s) __syncthreads();
    #pragma unroll
    for (int p = 0; p < 8; ++p)
      *reinterpret_cast<us4*>(As + (arow + p * 16) * SA + akq * 4) = pack4(ap[p]);
    #pragma unroll
    for (int p = 0; p < BP; ++p)
      *reinterpret_cast<bf16x8*>(Bs + (brow + p * 32) * SA + bkq * 8) = bp[p];
    if (s + 1 < nsteps) {
      #pragma unroll
      for (int p = 0; p < 8; ++p) ap[p] = *reinterpret_cast<const float4*>(agp[p] + 64);
      #pragma unroll
      for (int p = 0; p < BP; ++p) bp[p] = *reinterpret_cast<const bf16x8*>(bgp[p] + 64);
      #pragma unroll
      for (int p = 0; p < 8; ++p) agp[p] += 64;
      #pragma unroll
      for (int p = 0; p < BP; ++p) bgp[p] += 64;
    }
    __syncthreads();
    #pragma unroll
    for (int kh = 0; kh < 2; ++kh) {
      bf16x8 af[2];
      #pragma unroll
      for (int pi = 0; pi < 2; ++pi)
        af[pi] = *reinterpret_cast<bf16x8*>(As + ((wv * 2 + pi) * 16 + l15) * SA + kh * 32 + quad * 8);
      #pragma unroll
      for (int ct = 0; ct < NCT; ++ct) {
        bf16x8 bfr = *reinterpret_cast<bf16x8*>(Bs + (ct * 16 + l15) * SA + kh * 32 + quad * 8);
        acc[0][ct] = __builtin_amdgcn_mfma_f32_16x16x32_bf16(af[0], bfr, acc[0][ct], 0, 0, 0);
        acc[1][ct] = __builtin_amdgcn_mfma_f32_16x16x32_bf16(af[1], bfr, acc[1][ct], 0, 0, 0);
      }
    }
  }
  #pragma unroll
  for (int pi = 0; pi < 2; ++pi) {
    #pragma unroll
    for (int ct = 0; ct < NCT; ++ct) {
      int col = c0 + ct * 16 + l15;
      if (col < N) {
        #pragma unroll
        for (int r = 0; r < 4; ++r) {
          int row = r0 + (wv * 2 + pi) * 16 + quad * 4 + r;
          if (row < M) atomicAdd(&C[(size_t)row * N + col], acc[pi][ct][r]);
        }
      }
    }
  }
}

// ---------------- mega: gn (125) + img_h GEMM (64) + proto_red GEMM (96) ----------------
__global__ __launch_bounds__(256) void mega_k(
    const float* __restrict__ attributes, const float* __restrict__ att_g,
    ushort_t* __restrict__ gn_bf,
    const float* __restrict__ img_proto, const ushort_t* __restrict__ slimT,
    float* __restrict__ proto_red,
    const float* __restrict__ image_feats, const ushort_t* __restrict__ imgwT,
    float* __restrict__ img_h) {
  __shared__ ushort_t As[128 * 72];
  __shared__ ushort_t Bs[128 * 72];
  int b = blockIdx.x, tid = threadIdx.x;
  if (b < 125) {
    __shared__ float a_lds[8][316];
    __shared__ float red2[8][2];
    int h = tid & 127;
    int c0 = b * 8;
    for (int idx = tid; idx < 8 * 312; idx += 256) {
      int r = idx / 312;
      int k = idx - r * 312;
      a_lds[r][k] = attributes[(c0 + r) * 312 + k];
    }
    __syncthreads();
    float acc[8] = {0.f,0.f,0.f,0.f,0.f,0.f,0.f,0.f};
    for (int k = 0; k < 312; k += 4) {
      float w0 = att_g[(k + 0) * 128 + h];
      float w1 = att_g[(k + 1) * 128 + h];
      float w2 = att_g[(k + 2) * 128 + h];
      float w3 = att_g[(k + 3) * 128 + h];
      #pragma unroll
      for (int r = 0; r < 8; ++r) {
        float4 a4 = *reinterpret_cast<const float4*>(&a_lds[r][k]);
        acc[r] += a4.x * w0 + a4.y * w1 + a4.z * w2 + a4.w * w3;
      }
    }
    int lane = tid & 63, wvid = (tid >> 6) & 1;
    #pragma unroll
    for (int r = 0; r < 8; ++r) {
      float v = acc[r] * acc[r];
      #pragma unroll
      for (int off = 32; off > 0; off >>= 1) v += __shfl_xor(v, off, 64);
      if (lane == 0) red2[r][wvid] = v;
    }
    __syncthreads();
    #pragma unroll
    for (int r = 0; r < 8; ++r) {
      float nrm = fmaxf(sqrtf(red2[r][0] + red2[r][1]), 1e-12f);
      gn_bf[(c0 + r) * 128 + h] = f2bf(acc[r] / nrm);
    }
    return;
  }
  b -= 125;
  if (b < 64) {
    int rb = b >> 2, kc = b & 3;
    gemm_seg<8>(image_feats, 2048, 2048, imgwT, 2048, img_h, 128,
                rb * 128, 0, kc * 512, 8, As, Bs, tid);
  } else {
    b -= 64;
    int kc = b & 3; int t = b >> 2;
    int rb = t / 3, cb = t - rb * 3;
    if (cb == 2)
      gemm_seg<4>(img_proto, 1000, 2048, slimT, 2048, proto_red, 312,
                  rb * 128, 256, kc * 512, 8, As, Bs, tid);
    else
      gemm_seg<8>(img_proto, 1000, 2048, slimT, 2048, proto_red, 312,
                  rb * 128, cb * 128, kc * 512, 8, As, Bs, tid);
  }
}

// ---------------- trp: proto_red fp32 -> poutT rows 312..623 (bf16, transposed) + zero rows 624..639 ----------------
__global__ __launch_bounds__(256) void trp_k(const float* __restrict__ proto_red,
                                             ushort_t* __restrict__ poutT) {
  int b = blockIdx.x, tid = threadIdx.x;
  if (b >= 320) {               // zero rows 624..639: 16 x 1024 bf16
    int local = b - 320;        // 0..3
    us4 z = {0, 0, 0, 0};
    ushort_t* base = poutT + 624ull * 1024 + local * 4096;
    *reinterpret_cast<us4*>(base + tid * 16)      = z;
    *reinterpret_cast<us4*>(base + tid * 16 + 4)  = z;
    *reinterpret_cast<us4*>(base + tid * 16 + 8)  = z;
    *reinterpret_cast<us4*>(base + tid * 16 + 12) = z;
    return;
  }
  __shared__ float tl[32][33];
  int rt = b / 10, ct = b - rt * 10;
  int r0 = rt * 32, c0 = ct * 32;
  #pragma unroll
  for (int p = 0; p < 4; ++p) {
    int idx = p * 256 + tid;
    int rr = idx >> 5, cc = idx & 31;
    float v = 0.f;
    if (r0 + rr < 1000 && c0 + cc < 312) v = proto_red[(size_t)(r0 + rr) * 312 + (c0 + cc)];
    tl[cc][rr] = v;
  }
  __syncthreads();
  int cc = tid >> 3, rq = tid & 7;
  if (c0 + cc < 312) {
    us4 o;
    o[0] = f2bf(tl[cc][rq * 4 + 0]);
    o[1] = f2bf(tl[cc][rq * 4 + 1]);
    o[2] = f2bf(tl[cc][rq * 4 + 2]);
    o[3] = f2bf(tl[cc][rq * 4 + 3]);
    *reinterpret_cast<us4*>(poutT + (size_t)(312 + c0 + cc) * 1024 + r0 + rq * 4) = o;
  }
}

// ---------------- attn3: dense two-stage MFMA with hot-tile skip ----------------
// 63 blocks x 256 thr; 16 i-rows per block
__global__ __launch_bounds__(256) void attn3_k(
    const ushort_t* __restrict__ gn_bf, const ushort_t* __restrict__ poutT,
    const float* __restrict__ slim_b, ushort_t* __restrict__ outs) {
  __shared__ ushort_t W[16 * SW];
  __shared__ float rsum[16];
  __shared__ int flags[63];
  int tid = threadIdx.x;
  int i0 = blockIdx.x * 16;
  int lane = tid & 63, wv = tid >> 6;
  int l15 = lane & 15, quad = lane >> 4;
  if (tid < 63) flags[tid] = 0;
  if (tid >= 64 && tid < 80) rsum[tid - 64] = 0.f;
  W[(tid >> 4) * SW + 1008 + (tid & 15)] = 0;   // zero k-pad cols 1008..1023
  __syncthreads();

  // phase 1: sim rows i0..i0+15 vs all j, exp, W strip to LDS (A-layout), rowsums, hot flags
  const ushort_t* abase = gn_bf + (size_t)(i0 + l15) * 128 + quad * 8;
  bf16x8 af0 = *reinterpret_cast<const bf16x8*>(abase);
  bf16x8 af1 = *reinterpret_cast<const bf16x8*>(abase + 32);
  bf16x8 af2 = *reinterpret_cast<const bf16x8*>(abase + 64);
  bf16x8 af3 = *reinterpret_cast<const bf16x8*>(abase + 96);
  float rs[4] = {0.f, 0.f, 0.f, 0.f};
  for (int jt = wv; jt < 63; jt += 4) {
    const ushort_t* bbase = gn_bf + (size_t)(jt * 16 + l15) * 128 + quad * 8;
    f32x4 d = {0.f, 0.f, 0.f, 0.f};
    d = __builtin_amdgcn_mfma_f32_16x16x32_bf16(af0, *reinterpret_cast<const bf16x8*>(bbase),      d, 0, 0, 0);
    d = __builtin_amdgcn_mfma_f32_16x16x32_bf16(af1, *reinterpret_cast<const bf16x8*>(bbase + 32), d, 0, 0, 0);
    d = __builtin_amdgcn_mfma_f32_16x16x32_bf16(af2, *reinterpret_cast<const bf16x8*>(bbase + 64), d, 0, 0, 0);
    d = __builtin_amdgcn_mfma_f32_16x16x32_bf16(af3, *reinterpret_cast<const bf16x8*>(bbase + 96), d, 0, 0, 0);
    int hot = 0;
    #pragma unroll
    for (int r = 0; r < 4; ++r) {
      float w = 0.f;
      if (d[r] > THRESH) { w = __expf(T_SOFT * (d[r] - 1.0f)); hot = 1; }  // shift cancels in normalize
      ushort_t wb = f2bf(w);
      W[(quad * 4 + r) * SW + jt * 16 + l15] = wb;
      rs[r] += bf2f(wb);    // rowsum of ROUNDED weights: single-entry rows normalize exactly
    }
    if (hot) flags[jt] = 1;
  }
  #pragma unroll
  for (int r = 0; r < 4; ++r) {
    float v = rs[r];
    v += __shfl_xor(v, 1, 64); v += __shfl_xor(v, 2, 64);
    v += __shfl_xor(v, 4, 64); v += __shfl_xor(v, 8, 64);
    if (l15 == 0) atomicAdd(&rsum[quad * 4 + r], v);
  }
  __syncthreads();

  // phase 2: outs_strip = W @ poutT^T, skipping cold k-tiles; wave wv owns col tiles wv*10..wv*10+9
  f32x4 acc[10];
  #pragma unroll
  for (int t = 0; t < 10; ++t) acc[t] = f32x4{0.f, 0.f, 0.f, 0.f};
  for (int s = 0; s < 32; ++s) {
    int f = flags[2 * s] | ((2 * s + 1 < 63) ? flags[2 * s + 1] : 0);
    if (!f) continue;
    bf16x8 a = *reinterpret_cast<bf16x8*>(W + l15 * SW + s * 32 + quad * 8);
    #pragma unroll
    for (int t = 0; t < 10; ++t) {
      int nrow = (wv * 10 + t) * 16 + l15;
      bf16x8 bfr = *reinterpret_cast<const bf16x8*>(poutT + (size_t)nrow * 1024 + s * 32 + quad * 8);
      acc[t] = __builtin_amdgcn_mfma_f32_16x16x32_bf16(a, bfr, acc[t], 0, 0, 0);
    }
  }
  #pragma unroll
  for (int t = 0; t < 10; ++t) {
    int col = (wv * 10 + t) * 16 + l15;   // 0..639
    float bias = (col >= 312 && col < 624) ? slim_b[col - 312] : 0.f;
    #pragma unroll
    for (int r = 0; r < 4; ++r) {
      int gi = i0 + quad * 4 + r;
      if (gi < 1000) {
        float inv = 1.f / fmaxf(rsum[quad * 4 + r], 1e-30f);
        outs[(size_t)gi * 640 + col] = f2bf(acc[t][r] * inv + bias);
      }
    }
  }
}

// ---------------- bf16 MFMA GEMM (ph = outs @ proto_w + proto_b) ----------------
__global__ __launch_bounds__(256) void mfma_gemm_bt(
    const ushort_t* __restrict__ A, const ushort_t* __restrict__ BT,
    float* __restrict__ C, int M, int N, int K, int Mt, int Nt,
    const float* __restrict__ bias) {
  int wid = blockIdx.x * 4 + (threadIdx.x >> 6);
  int lane = threadIdx.x & 63;
  int tm = wid / Nt;
  int tn = wid - tm * Nt;
  if (tm >= Mt) return;
  int l15 = lane & 15;
  int quad = lane >> 4;
  const bf16x8* ap = reinterpret_cast<const bf16x8*>(A + (size_t)(tm * 16 + l15) * K + quad * 8);
  const bf16x8* bp = reinterpret_cast<const bf16x8*>(BT + (size_t)(tn * 16 + l15) * K + quad * 8);
  f32x4 acc = {0.f, 0.f, 0.f, 0.f};
  for (int s = 0, steps = K >> 7; s < steps; ++s) {
    bf16x8 a0 = ap[0],  b0 = bp[0];
    bf16x8 a1 = ap[4],  b1 = bp[4];
    bf16x8 a2 = ap[8],  b2 = bp[8];
    bf16x8 a3 = ap[12], b3 = bp[12];
    ap += 16; bp += 16;
    acc = __builtin_amdgcn_mfma_f32_16x16x32_bf16(a0, b0, acc, 0, 0, 0);
    acc = __builtin_amdgcn_mfma_f32_16x16x32_bf16(a1, b1, acc, 0, 0, 0);
    acc = __builtin_amdgcn_mfma_f32_16x16x32_bf16(a2, b2, acc, 0, 0, 0);
    acc = __builtin_amdgcn_mfma_f32_16x16x32_bf16(a3, b3, acc, 0, 0, 0);
  }
  int col = tn * 16 + l15;
  if (col >= N) return;
  float bv = bias ? bias[col] : 0.f;
  int row0 = tm * 16 + quad * 4;
  #pragma unroll
  for (int r = 0; r < 4; ++r) {
    int row = row0 + r;
    if (row < M) C[(size_t)row * N + col] = acc[r] + bv;
  }
}

// ---------------- final: out[b,c] = fc_b + sum_h relu(img_h[b,h]+ph[c,h]) * fc_w[h] ----------------
__global__ __launch_bounds__(256) void final_k(
    const float* __restrict__ img_h, const float* __restrict__ ph,
    const float* __restrict__ fc_w, const float* __restrict__ fc_b,
    float* __restrict__ out) {
  __shared__ float ih[128][132];
  __shared__ float ps[64][132];
  __shared__ float ws_[128];
  int tid = threadIdx.x;
  int b0 = blockIdx.x * 128;
  int c0 = blockIdx.y * 64;
  for (int idx = tid; idx < 4096; idx += 256) {
    int row = idx >> 5, c4 = (idx & 31) * 4;
    float4 v = *reinterpret_cast<const float4*>(img_h + (size_t)(b0 + row) * 128 + c4);
    *reinterpret_cast<float4*>(&ih[row][c4]) = v;
  }
  for (int idx = tid; idx < 2048; idx += 256) {
    int row = idx >> 5, c4 = (idx & 31) * 4;
    int c = c0 + row;
    float4 v = make_float4(0.f, 0.f, 0.f, 0.f);
    if (c < 1000) v = *reinterpret_cast<const float4*>(ph + (size_t)c * 128 + c4);
    *reinterpret_cast<float4*>(&ps[row][c4]) = v;
  }
  if (tid < 128) ws_[tid] = fc_w[tid];
  __syncthreads();
  int tx = tid & 15, ty = tid >> 4;
  f32x2 acc[8][4] = {};
  const f32x2 zero2 = {0.f, 0.f};
  for (int h = 0; h < 128; h += 4) {
    float4 w4 = *reinterpret_cast<float4*>(&ws_[h]);
    f32x2 wlo = {w4.x, w4.y}, whi = {w4.z, w4.w};
    float4 a4[8], p4[4];
    #pragma unroll
    for (int i = 0; i < 8; ++i) a4[i] = *reinterpret_cast<float4*>(&ih[ty * 8 + i][h]);
    #pragma unroll
    for (int j = 0; j < 4; ++j) p4[j] = *reinterpret_cast<float4*>(&ps[tx * 4 + j][h]);
    #pragma unroll
    for (int i = 0; i < 8; ++i) {
      f32x2 alo = {a4[i].x, a4[i].y}, ahi = {a4[i].z, a4[i].w};
      #pragma unroll
      for (int j = 0; j < 4; ++j) {
        f32x2 plo = {p4[j].x, p4[j].y}, phi = {p4[j].z, p4[j].w};
        f32x2 t0 = __builtin_elementwise_max(alo + plo, zero2);
        f32x2 t1 = __builtin_elementwise_max(ahi + phi, zero2);
        acc[i][j] = acc[i][j] + t0 * wlo;
        acc[i][j] = acc[i][j] + t1 * whi;
      }
    }
  }
  float fb = fc_b[0];
  #pragma unroll
  for (int i = 0; i < 8; ++i) {
    int b = b0 + ty * 8 + i;
    int c = c0 + tx * 4;
    if (c < 1000) {
      float4 v = make_float4(acc[i][0].x + acc[i][0].y + fb, acc[i][1].x + acc[i][1].y + fb,
                             acc[i][2].x + acc[i][2].y + fb, acc[i][3].x + acc[i][3].y + fb);
      *reinterpret_cast<float4*>(out + (size_t)b * 1000 + c) = v;
    }
  }
}

extern "C" void kernel_launch(void* const* d_in, const int* in_sizes, int n_in,
                              void* d_out, int out_size, void* d_ws, size_t ws_size,
                              hipStream_t stream) {
  const float* image_feats = (const float*)d_in[0];   // [2048,2048]
  const float* img_proto   = (const float*)d_in[1];   // [1000,2048]
  const float* attributes  = (const float*)d_in[2];   // [1000,312]
  const float* att_g   = (const float*)d_in[4];       // [312,128]
  const float* slim_w  = (const float*)d_in[5];       // [2048,312]
  const float* slim_b  = (const float*)d_in[6];       // [312]
  const float* img_w   = (const float*)d_in[7];       // [2048,128]
  const float* proto_w = (const float*)d_in[8];       // [624,128]
  const float* proto_b = (const float*)d_in[9];       // [1,128]
  const float* fc_w    = (const float*)d_in[10];      // [128,1]
  const float* fc_b    = (const float*)d_in[11];      // [1]
  float* out = (float*)d_out;                         // [2048,1000]

  char* ws = (char*)d_ws;
  size_t o = 0;
  auto alloc = [&](size_t bytes) { size_t r = o; o += (bytes + 255) & ~(size_t)255; return r; };
  ushort_t* imgwT   = (ushort_t*)(ws + alloc(128ull * 2048 * 2));   // img_w^T bf16
  ushort_t* slimT   = (ushort_t*)(ws + alloc(320ull * 2048 * 2));   // slim_w^T bf16
  ushort_t* protowT = (ushort_t*)(ws + alloc(128ull * 640 * 2));    // proto_w^T bf16, K-pad zeros
  ushort_t* gn_bf   = (ushort_t*)(ws + alloc(1008ull * 128 * 2));   // normalized g bf16, tail zero
  float* proto_red = (float*)(ws + alloc(1000ull * 312 * 4));       // split-K atomic target (no bias)
  ushort_t* poutT   = (ushort_t*)(ws + alloc(640ull * 1024 * 2));   // [attrT; proto_redT; 0] bf16
  ushort_t* outs_bf = (ushort_t*)(ws + alloc(1008ull * 640 * 2));   // concat outs bf16
  float* img_h     = (float*)(ws + alloc(2048ull * 128 * 4));       // split-K atomic target
  float* ph        = (float*)(ws + alloc(1000ull * 128 * 4));

  // transposes (976) + attrT (320) + zero img_h (64) + zero proto_red (77) + gn tail (1)
  tr3_k<<<1438, 256, 0, stream>>>(slim_w, slimT, img_w, imgwT, proto_w, protowT,
                                  attributes, poutT, img_h, proto_red, gn_bf);

  // gn (125) + img_h GEMM (64) + proto_red GEMM (96)
  mega_k<<<285, 256, 0, stream>>>(attributes, att_g, gn_bf,
                                  img_proto, slimT, proto_red,
                                  image_feats, imgwT, img_h);

  // proto_red -> poutT rows 312..623 (transposed bf16) + zero rows 624..639
  trp_k<<<324, 256, 0, stream>>>(proto_red, poutT);

  attn3_k<<<63, 256, 0, stream>>>(gn_bf, poutT, slim_b, outs_bf);

  // ph = outs @ proto_w + proto_b   (M=1000,N=128,K=640)
  mfma_gemm_bt<<<126, 256, 0, stream>>>(outs_bf, protowT, ph, 1000, 128, 640, 63, 8, proto_b);

  final_k<<<dim3(16, 16), 256, 0, stream>>>(img_h, ph, fc_w, fc_b, out);
}

// Round 6
// 175.717 us; speedup vs baseline: 1.2700x; 1.0398x over previous
//
#include <hip/hip_runtime.h>

typedef unsigned short ushort_t;
typedef __bf16 bf16x8 __attribute__((ext_vector_type(8)));
typedef float f32x4 __attribute__((ext_vector_type(4)));
typedef float f32x2 __attribute__((ext_vector_type(2)));
typedef ushort_t us4 __attribute__((ext_vector_type(4)));

#define T_SOFT 32.0f
#define THRESH 0.76604444311897803f   // cos(40 deg)
#define SW 1048                       // W strip LDS row stride (bf16)
#define SO 648                        // outs strip LDS row stride (bf16)

__device__ __forceinline__ ushort_t f2bf(float f) {
  union { float f; unsigned u; } x; x.f = f;
  unsigned r = (x.u + 0x7fffu + ((x.u >> 16) & 1u)) >> 16;  // RNE
  return (ushort_t)r;
}
__device__ __forceinline__ float bf2f(ushort_t h) {
  union { unsigned u; float f; } x; x.u = ((unsigned)h) << 16; return x.f;
}

// pack 4 fp32 -> 4 bf16 (round-half-up via +0x8000 + byte perm)
__device__ __forceinline__ us4 pack4(float4 x) {
  union { unsigned u[2]; us4 h; } r;
  union { float4 f; unsigned u[4]; } a;
  a.f = x;
  r.u[0] = __builtin_amdgcn_perm(a.u[1] + 0x8000u, a.u[0] + 0x8000u, 0x07060302u);
  r.u[1] = __builtin_amdgcn_perm(a.u[3] + 0x8000u, a.u[2] + 0x8000u, 0x07060302u);
  return r.h;
}

// ---------------- tr3: transposes + attrT + zero tails ----------------
__global__ __launch_bounds__(256) void tr3_k(const float* __restrict__ s0, ushort_t* __restrict__ d0,
                                             const float* __restrict__ s1, ushort_t* __restrict__ d1,
                                             const float* __restrict__ s2, ushort_t* __restrict__ d2,
                                             const float* __restrict__ s3, ushort_t* __restrict__ d3,
                                             ushort_t* __restrict__ gn_bf, ushort_t* __restrict__ poutT) {
  int b = blockIdx.x, tid = threadIdx.x;
  if (b >= 1296) {
    us4 z = {0, 0, 0, 0};
    if (b == 1296) {          // zero gn_bf rows 1000..1007 (1024 bf16)
      *reinterpret_cast<us4*>(gn_bf + 1000 * 128 + tid * 4) = z;
    } else {                  // zero poutT rows 632..639 (8 x 1024 bf16)
      ushort_t* base = poutT + 632ull * 1024 + tid * 32;
      #pragma unroll
      for (int i = 0; i < 8; ++i) *reinterpret_cast<us4*>(base + i * 4) = z;
    }
    return;
  }
  __shared__ float tl[32][33];
  const float* src; ushort_t* dst; int R, C, Cw, Rpad, local, ctiles;
  if (b < 640)       { src = s0; dst = d0; R = 2048; C = 312; Cw = 320; Rpad = 2048; local = b;       ctiles = 10; }
  else if (b < 896)  { src = s1; dst = d1; R = 2048; C = 128; Cw = 128; Rpad = 2048; local = b - 640; ctiles = 4;  }
  else if (b < 976)  { src = s2; dst = d2; R = 624;  C = 128; Cw = 128; Rpad = 640;  local = b - 896; ctiles = 4;  }
  else               { src = s3; dst = d3; R = 1000; C = 312; Cw = 312; Rpad = 1024; local = b - 976; ctiles = 10; }
  int rt = local / ctiles, ct = local - rt * ctiles;
  int r0 = rt * 32, c0 = ct * 32;
  #pragma unroll
  for (int p = 0; p < 4; ++p) {
    int idx = p * 256 + tid;
    int rr = idx >> 5, cc = idx & 31;
    float v = 0.f;
    if (r0 + rr < R && c0 + cc < C) v = src[(size_t)(r0 + rr) * C + (c0 + cc)];
    tl[cc][rr] = v;
  }
  __syncthreads();
  int cc = tid >> 3, rq = tid & 7;
  if (c0 + cc < Cw) {   // slim region: cols 312..319 write ZEROS (pad rows of slimT)
    us4 o;
    o[0] = f2bf(tl[cc][rq * 4 + 0]);
    o[1] = f2bf(tl[cc][rq * 4 + 1]);
    o[2] = f2bf(tl[cc][rq * 4 + 2]);
    o[3] = f2bf(tl[cc][rq * 4 + 3]);
    *reinterpret_cast<us4*>(dst + (size_t)(c0 + cc) * Rpad + r0 + rq * 4) = o;
  }
}

// ---------------- img_h GEMM block: full-K, direct fp32 store ----------------
// C[r0..r0+127][0..127] = A(fp32,[2048x2048]) @ imgwT(bf16,[128x2048])^T
__device__ __forceinline__ void gemm_imgh(const float* __restrict__ A, const ushort_t* __restrict__ BT,
                                          float* __restrict__ C, int r0,
                                          ushort_t* __restrict__ As, ushort_t* __restrict__ Bs, int tid) {
  const int SA = 72;
  int lane = tid & 63, wv = tid >> 6;
  int l15 = lane & 15, quad = lane >> 4;
  int arow = tid >> 4, akq = tid & 15;
  int brow = tid >> 3, bkq = tid & 7;
  const float* agp[8];
  #pragma unroll
  for (int p = 0; p < 8; ++p) agp[p] = A + (size_t)(r0 + arow + p * 16) * 2048 + akq * 4;
  const ushort_t* bgp[4];
  #pragma unroll
  for (int p = 0; p < 4; ++p) bgp[p] = BT + (size_t)(brow + p * 32) * 2048 + bkq * 8;

  float4 ap[8]; bf16x8 bp[4];
  #pragma unroll
  for (int p = 0; p < 8; ++p) ap[p] = *reinterpret_cast<const float4*>(agp[p]);
  #pragma unroll
  for (int p = 0; p < 4; ++p) bp[p] = *reinterpret_cast<const bf16x8*>(bgp[p]);

  f32x4 acc[2][8];
  #pragma unroll
  for (int i = 0; i < 2; ++i)
    #pragma unroll
    for (int j = 0; j < 8; ++j) acc[i][j] = f32x4{0.f, 0.f, 0.f, 0.f};

  for (int s = 0; s < 32; ++s) {
    if (s) __syncthreads();
    #pragma unroll
    for (int p = 0; p < 8; ++p)
      *reinterpret_cast<us4*>(As + (arow + p * 16) * SA + akq * 4) = pack4(ap[p]);
    #pragma unroll
    for (int p = 0; p < 4; ++p)
      *reinterpret_cast<bf16x8*>(Bs + (brow + p * 32) * SA + bkq * 8) = bp[p];
    if (s + 1 < 32) {
      #pragma unroll
      for (int p = 0; p < 8; ++p) ap[p] = *reinterpret_cast<const float4*>(agp[p] + 64);
      #pragma unroll
      for (int p = 0; p < 4; ++p) bp[p] = *reinterpret_cast<const bf16x8*>(bgp[p] + 64);
      #pragma unroll
      for (int p = 0; p < 8; ++p) agp[p] += 64;
      #pragma unroll
      for (int p = 0; p < 4; ++p) bgp[p] += 64;
    }
    __syncthreads();
    #pragma unroll
    for (int kh = 0; kh < 2; ++kh) {
      bf16x8 af[2];
      #pragma unroll
      for (int pi = 0; pi < 2; ++pi)
        af[pi] = *reinterpret_cast<bf16x8*>(As + ((wv * 2 + pi) * 16 + l15) * SA + kh * 32 + quad * 8);
      #pragma unroll
      for (int ct = 0; ct < 8; ++ct) {
        bf16x8 bfr = *reinterpret_cast<bf16x8*>(Bs + (ct * 16 + l15) * SA + kh * 32 + quad * 8);
        acc[0][ct] = __builtin_amdgcn_mfma_f32_16x16x32_bf16(af[0], bfr, acc[0][ct], 0, 0, 0);
        acc[1][ct] = __builtin_amdgcn_mfma_f32_16x16x32_bf16(af[1], bfr, acc[1][ct], 0, 0, 0);
      }
    }
  }
  #pragma unroll
  for (int pi = 0; pi < 2; ++pi)
    #pragma unroll
    for (int ct = 0; ct < 8; ++ct) {
      int col = ct * 16 + l15;
      #pragma unroll
      for (int r = 0; r < 4; ++r) {
        int row = r0 + (wv * 2 + pi) * 16 + quad * 4 + r;
        C[(size_t)row * 128 + col] = acc[pi][ct][r];
      }
    }
}

// ---------------- proto_redT GEMM block: full-K, bf16 store into poutT rows 312.. ----------------
// poutT[312+m][n] = sum_k slimT[m][k] * img_proto[n][k];  m in [r0,r0+128), n in [c0,c0+128)
__device__ __forceinline__ void gemm_protoT(const ushort_t* __restrict__ A, const float* __restrict__ B,
                                            ushort_t* __restrict__ poutT, int r0, int c0,
                                            ushort_t* __restrict__ As, ushort_t* __restrict__ Bs, int tid) {
  const int SA = 72;
  int lane = tid & 63, wv = tid >> 6;
  int l15 = lane & 15, quad = lane >> 4;
  int frow = tid >> 4, fkq = tid & 15;   // fp32 staging: 16 rows/pass x 16 float4 lanes
  int hrow = tid >> 3, hkq = tid & 7;    // bf16 staging: 32 rows/pass x 8 b128 lanes
  const ushort_t* agp[4];
  #pragma unroll
  for (int p = 0; p < 4; ++p) {
    int r = r0 + hrow + p * 32; if (r >= 320) r = 319;
    agp[p] = A + (size_t)r * 2048 + hkq * 8;
  }
  const float* bgp[8];
  #pragma unroll
  for (int p = 0; p < 8; ++p) {
    int n = c0 + frow + p * 16; if (n >= 1000) n = 999;
    bgp[p] = B + (size_t)n * 2048 + fkq * 4;
  }
  bf16x8 ar[4]; float4 br[8];
  #pragma unroll
  for (int p = 0; p < 4; ++p) ar[p] = *reinterpret_cast<const bf16x8*>(agp[p]);
  #pragma unroll
  for (int p = 0; p < 8; ++p) br[p] = *reinterpret_cast<const float4*>(bgp[p]);

  f32x4 acc[2][8];
  #pragma unroll
  for (int i = 0; i < 2; ++i)
    #pragma unroll
    for (int j = 0; j < 8; ++j) acc[i][j] = f32x4{0.f, 0.f, 0.f, 0.f};

  for (int s = 0; s < 32; ++s) {
    if (s) __syncthreads();
    #pragma unroll
    for (int p = 0; p < 4; ++p)
      *reinterpret_cast<bf16x8*>(As + (hrow + p * 32) * SA + hkq * 8) = ar[p];
    #pragma unroll
    for (int p = 0; p < 8; ++p)
      *reinterpret_cast<us4*>(Bs + (frow + p * 16) * SA + fkq * 4) = pack4(br[p]);
    if (s + 1 < 32) {
      #pragma unroll
      for (int p = 0; p < 4; ++p) ar[p] = *reinterpret_cast<const bf16x8*>(agp[p] + 64);
      #pragma unroll
      for (int p = 0; p < 8; ++p) br[p] = *reinterpret_cast<const float4*>(bgp[p] + 64);
      #pragma unroll
      for (int p = 0; p < 4; ++p) agp[p] += 64;
      #pragma unroll
      for (int p = 0; p < 8; ++p) bgp[p] += 64;
    }
    __syncthreads();
    #pragma unroll
    for (int kh = 0; kh < 2; ++kh) {
      bf16x8 af[2];
      #pragma unroll
      for (int pi = 0; pi < 2; ++pi)
        af[pi] = *reinterpret_cast<bf16x8*>(As + ((wv * 2 + pi) * 16 + l15) * SA + kh * 32 + quad * 8);
      #pragma unroll
      for (int ct = 0; ct < 8; ++ct) {
        bf16x8 bfr = *reinterpret_cast<bf16x8*>(Bs + (ct * 16 + l15) * SA + kh * 32 + quad * 8);
        acc[0][ct] = __builtin_amdgcn_mfma_f32_16x16x32_bf16(af[0], bfr, acc[0][ct], 0, 0, 0);
        acc[1][ct] = __builtin_amdgcn_mfma_f32_16x16x32_bf16(af[1], bfr, acc[1][ct], 0, 0, 0);
      }
    }
  }
  #pragma unroll
  for (int pi = 0; pi < 2; ++pi)
    #pragma unroll
    for (int ct = 0; ct < 8; ++ct) {
      int n = c0 + ct * 16 + l15;
      if (n < 1000) {
        #pragma unroll
        for (int r = 0; r < 4; ++r) {
          int m = r0 + (wv * 2 + pi) * 16 + quad * 4 + r;
          if (m < 320) poutT[(size_t)(312 + m) * 1024 + n] = f2bf(acc[pi][ct][r]);
        }
      }
    }
}

// ---------------- mega: gn (125) + img_h (16) + proto_redT (24) ----------------
__global__ __launch_bounds__(256) void mega_k(
    const float* __restrict__ attributes, const float* __restrict__ att_g,
    ushort_t* __restrict__ gn_bf,
    const float* __restrict__ img_proto, const ushort_t* __restrict__ slimT,
    const float* __restrict__ image_feats, const ushort_t* __restrict__ imgwT,
    float* __restrict__ img_h, ushort_t* __restrict__ poutT) {
  __shared__ ushort_t As[128 * 72];
  __shared__ ushort_t Bs[128 * 72];
  int b = blockIdx.x, tid = threadIdx.x;
  if (b < 125) {
    __shared__ float a_lds[8][316];
    __shared__ float red2[8][2];
    int h = tid & 127;
    int c0 = b * 8;
    for (int idx = tid; idx < 8 * 312; idx += 256) {
      int r = idx / 312;
      int k = idx - r * 312;
      a_lds[r][k] = attributes[(c0 + r) * 312 + k];
    }
    __syncthreads();
    float acc[8] = {0.f,0.f,0.f,0.f,0.f,0.f,0.f,0.f};
    for (int k = 0; k < 312; k += 4) {
      float w0 = att_g[(k + 0) * 128 + h];
      float w1 = att_g[(k + 1) * 128 + h];
      float w2 = att_g[(k + 2) * 128 + h];
      float w3 = att_g[(k + 3) * 128 + h];
      #pragma unroll
      for (int r = 0; r < 8; ++r) {
        float4 a4 = *reinterpret_cast<const float4*>(&a_lds[r][k]);
        acc[r] += a4.x * w0 + a4.y * w1 + a4.z * w2 + a4.w * w3;
      }
    }
    int lane = tid & 63, wvid = (tid >> 6) & 1;
    #pragma unroll
    for (int r = 0; r < 8; ++r) {
      float v = acc[r] * acc[r];
      #pragma unroll
      for (int off = 32; off > 0; off >>= 1) v += __shfl_xor(v, off, 64);
      if (lane == 0) red2[r][wvid] = v;   // duplicate waves write identical values
    }
    __syncthreads();
    #pragma unroll
    for (int r = 0; r < 8; ++r) {
      float nrm = fmaxf(sqrtf(red2[r][0] + red2[r][1]), 1e-12f);
      gn_bf[(c0 + r) * 128 + h] = f2bf(acc[r] / nrm);
    }
    return;
  }
  b -= 125;
  if (b < 16) {
    gemm_imgh(image_feats, imgwT, img_h, b * 128, As, Bs, tid);
  } else {
    b -= 16;
    int rb = b >> 3, cb = b & 7;
    gemm_protoT(slimT, img_proto, poutT, rb * 128, cb * 128, As, Bs, tid);
  }
}

// ---------------- attn4: sim -> masked softmax -> propagate -> ph, all fused ----------------
// 63 blocks x 256 thr; 16 i-rows per block
__global__ __launch_bounds__(256) void attn4_k(
    const ushort_t* __restrict__ gn_bf, const ushort_t* __restrict__ poutT,
    const float* __restrict__ slim_b, const ushort_t* __restrict__ protowT,
    const float* __restrict__ proto_b, float* __restrict__ ph) {
  __shared__ ushort_t W[16 * SW];
  __shared__ ushort_t OS[16 * SO];
  __shared__ float rsum[16];
  __shared__ int flags[63];
  int tid = threadIdx.x;
  int i0 = blockIdx.x * 16;
  int lane = tid & 63, wv = tid >> 6;
  int l15 = lane & 15, quad = lane >> 4;
  if (tid < 63) flags[tid] = 0;
  if (tid >= 64 && tid < 80) rsum[tid - 64] = 0.f;
  W[(tid >> 4) * SW + 1008 + (tid & 15)] = 0;   // zero k-pad cols 1008..1023
  __syncthreads();

  // phase 1: sim rows i0..i0+15 vs all j; exp; W strip -> LDS; rowsums; hot flags
  const ushort_t* abase = gn_bf + (size_t)(i0 + l15) * 128 + quad * 8;
  bf16x8 af0 = *reinterpret_cast<const bf16x8*>(abase);
  bf16x8 af1 = *reinterpret_cast<const bf16x8*>(abase + 32);
  bf16x8 af2 = *reinterpret_cast<const bf16x8*>(abase + 64);
  bf16x8 af3 = *reinterpret_cast<const bf16x8*>(abase + 96);
  float rs[4] = {0.f, 0.f, 0.f, 0.f};
  for (int jt = wv; jt < 63; jt += 4) {
    const ushort_t* bbase = gn_bf + (size_t)(jt * 16 + l15) * 128 + quad * 8;
    f32x4 d = {0.f, 0.f, 0.f, 0.f};
    d = __builtin_amdgcn_mfma_f32_16x16x32_bf16(af0, *reinterpret_cast<const bf16x8*>(bbase),      d, 0, 0, 0);
    d = __builtin_amdgcn_mfma_f32_16x16x32_bf16(af1, *reinterpret_cast<const bf16x8*>(bbase + 32), d, 0, 0, 0);
    d = __builtin_amdgcn_mfma_f32_16x16x32_bf16(af2, *reinterpret_cast<const bf16x8*>(bbase + 64), d, 0, 0, 0);
    d = __builtin_amdgcn_mfma_f32_16x16x32_bf16(af3, *reinterpret_cast<const bf16x8*>(bbase + 96), d, 0, 0, 0);
    int hot = 0;
    #pragma unroll
    for (int r = 0; r < 4; ++r) {
      float w = 0.f;
      if (d[r] > THRESH) { w = __expf(T_SOFT * (d[r] - 1.0f)); hot = 1; }  // shift cancels in normalize
      ushort_t wb = f2bf(w);
      W[(quad * 4 + r) * SW + jt * 16 + l15] = wb;
      rs[r] += bf2f(wb);    // rowsum of ROUNDED weights
    }
    if (hot) flags[jt] = 1;
  }
  #pragma unroll
  for (int r = 0; r < 4; ++r) {
    float v = rs[r];
    v += __shfl_xor(v, 1, 64); v += __shfl_xor(v, 2, 64);
    v += __shfl_xor(v, 4, 64); v += __shfl_xor(v, 8, 64);
    if (l15 == 0) atomicAdd(&rsum[quad * 4 + r], v);
  }
  __syncthreads();

  // phase 2: outs_strip = W @ poutT^T (skip cold k-tiles); wave wv owns col tiles wv*10..wv*10+9
  f32x4 acc[10];
  #pragma unroll
  for (int t = 0; t < 10; ++t) acc[t] = f32x4{0.f, 0.f, 0.f, 0.f};
  for (int s = 0; s < 32; ++s) {
    int f = flags[2 * s] | ((2 * s + 1 < 63) ? flags[2 * s + 1] : 0);
    if (!f) continue;
    bf16x8 a = *reinterpret_cast<bf16x8*>(W + l15 * SW + s * 32 + quad * 8);
    #pragma unroll
    for (int t = 0; t < 10; ++t) {
      int nrow = (wv * 10 + t) * 16 + l15;
      bf16x8 bfr = *reinterpret_cast<const bf16x8*>(poutT + (size_t)nrow * 1024 + s * 32 + quad * 8);
      acc[t] = __builtin_amdgcn_mfma_f32_16x16x32_bf16(a, bfr, acc[t], 0, 0, 0);
    }
  }
  // normalize + bias -> OS (A-layout for phase 3)
  #pragma unroll
  for (int t = 0; t < 10; ++t) {
    int col = (wv * 10 + t) * 16 + l15;   // 0..639
    float bias = (col >= 312 && col < 624) ? slim_b[col - 312] : 0.f;
    #pragma unroll
    for (int r = 0; r < 4; ++r) {
      int row = quad * 4 + r;
      float inv = 1.f / fmaxf(rsum[row], 1e-30f);
      OS[row * SO + col] = f2bf(acc[t][r] * inv + bias);
    }
  }
  __syncthreads();

  // phase 3: ph_strip = OS(16x640) @ protowT(128x640)^T + proto_b
  f32x4 acc2[2];
  acc2[0] = f32x4{0.f, 0.f, 0.f, 0.f};
  acc2[1] = f32x4{0.f, 0.f, 0.f, 0.f};
  for (int s = 0; s < 20; ++s) {
    bf16x8 a = *reinterpret_cast<bf16x8*>(OS + l15 * SO + s * 32 + quad * 8);
    #pragma unroll
    for (int t = 0; t < 2; ++t) {
      int n = (wv * 2 + t) * 16 + l15;
      bf16x8 bfr = *reinterpret_cast<const bf16x8*>(protowT + (size_t)n * 640 + s * 32 + quad * 8);
      acc2[t] = __builtin_amdgcn_mfma_f32_16x16x32_bf16(a, bfr, acc2[t], 0, 0, 0);
    }
  }
  #pragma unroll
  for (int t = 0; t < 2; ++t) {
    int h = (wv * 2 + t) * 16 + l15;
    float pb = proto_b[h];
    #pragma unroll
    for (int r = 0; r < 4; ++r) {
      int gi = i0 + quad * 4 + r;
      if (gi < 1000) ph[(size_t)gi * 128 + h] = acc2[t][r] + pb;
    }
  }
}

// ---------------- final: out[b,c] = fc_b + sum_h relu(img_h[b,h]+ph[c,h]) * fc_w[h] ----------------
__global__ __launch_bounds__(256) void final_k(
    const float* __restrict__ img_h, const float* __restrict__ ph,
    const float* __restrict__ fc_w, const float* __restrict__ fc_b,
    float* __restrict__ out) {
  __shared__ float ih[128][132];
  __shared__ float ps[64][132];
  __shared__ float ws_[128];
  int tid = threadIdx.x;
  int b0 = blockIdx.x * 128;
  int c0 = blockIdx.y * 64;
  for (int idx = tid; idx < 4096; idx += 256) {
    int row = idx >> 5, c4 = (idx & 31) * 4;
    float4 v = *reinterpret_cast<const float4*>(img_h + (size_t)(b0 + row) * 128 + c4);
    *reinterpret_cast<float4*>(&ih[row][c4]) = v;
  }
  for (int idx = tid; idx < 2048; idx += 256) {
    int row = idx >> 5, c4 = (idx & 31) * 4;
    int c = c0 + row;
    float4 v = make_float4(0.f, 0.f, 0.f, 0.f);
    if (c < 1000) v = *reinterpret_cast<const float4*>(ph + (size_t)c * 128 + c4);
    *reinterpret_cast<float4*>(&ps[row][c4]) = v;
  }
  if (tid < 128) ws_[tid] = fc_w[tid];
  __syncthreads();
  int tx = tid & 15, ty = tid >> 4;
  f32x2 acc[8][4] = {};
  const f32x2 zero2 = {0.f, 0.f};
  for (int h = 0; h < 128; h += 4) {
    float4 w4 = *reinterpret_cast<float4*>(&ws_[h]);
    f32x2 wlo = {w4.x, w4.y}, whi = {w4.z, w4.w};
    float4 a4[8], p4[4];
    #pragma unroll
    for (int i = 0; i < 8; ++i) a4[i] = *reinterpret_cast<float4*>(&ih[ty * 8 + i][h]);
    #pragma unroll
    for (int j = 0; j < 4; ++j) p4[j] = *reinterpret_cast<float4*>(&ps[tx * 4 + j][h]);
    #pragma unroll
    for (int i = 0; i < 8; ++i) {
      f32x2 alo = {a4[i].x, a4[i].y}, ahi = {a4[i].z, a4[i].w};
      #pragma unroll
      for (int j = 0; j < 4; ++j) {
        f32x2 plo = {p4[j].x, p4[j].y}, phi = {p4[j].z, p4[j].w};
        f32x2 t0 = __builtin_elementwise_max(alo + plo, zero2);
        f32x2 t1 = __builtin_elementwise_max(ahi + phi, zero2);
        acc[i][j] = acc[i][j] + t0 * wlo;
        acc[i][j] = acc[i][j] + t1 * whi;
      }
    }
  }
  float fb = fc_b[0];
  #pragma unroll
  for (int i = 0; i < 8; ++i) {
    int b = b0 + ty * 8 + i;
    int c = c0 + tx * 4;
    if (c < 1000) {
      float4 v = make_float4(acc[i][0].x + acc[i][0].y + fb, acc[i][1].x + acc[i][1].y + fb,
                             acc[i][2].x + acc[i][2].y + fb, acc[i][3].x + acc[i][3].y + fb);
      *reinterpret_cast<float4*>(out + (size_t)b * 1000 + c) = v;
    }
  }
}

extern "C" void kernel_launch(void* const* d_in, const int* in_sizes, int n_in,
                              void* d_out, int out_size, void* d_ws, size_t ws_size,
                              hipStream_t stream) {
  const float* image_feats = (const float*)d_in[0];   // [2048,2048]
  const float* img_proto   = (const float*)d_in[1];   // [1000,2048]
  const float* attributes  = (const float*)d_in[2];   // [1000,312]
  const float* att_g   = (const float*)d_in[4];       // [312,128]
  const float* slim_w  = (const float*)d_in[5];       // [2048,312]
  const float* slim_b  = (const float*)d_in[6];       // [312]
  const float* img_w   = (const float*)d_in[7];       // [2048,128]
  const float* proto_w = (const float*)d_in[8];       // [624,128]
  const float* proto_b = (const float*)d_in[9];       // [1,128]
  const float* fc_w    = (const float*)d_in[10];      // [128,1]
  const float* fc_b    = (const float*)d_in[11];      // [1]
  float* out = (float*)d_out;                         // [2048,1000]

  char* ws = (char*)d_ws;
  size_t o = 0;
  auto alloc = [&](size_t bytes) { size_t r = o; o += (bytes + 255) & ~(size_t)255; return r; };
  ushort_t* imgwT   = (ushort_t*)(ws + alloc(128ull * 2048 * 2));   // img_w^T bf16
  ushort_t* slimT   = (ushort_t*)(ws + alloc(320ull * 2048 * 2));   // slim_w^T bf16, rows 312..319 ZERO
  ushort_t* protowT = (ushort_t*)(ws + alloc(128ull * 640 * 2));    // proto_w^T bf16, K-pad zeros
  ushort_t* gn_bf   = (ushort_t*)(ws + alloc(1008ull * 128 * 2));   // normalized g bf16, tail zero
  ushort_t* poutT   = (ushort_t*)(ws + alloc(640ull * 1024 * 2));   // [attrT; proto_redT; 0] bf16
  float* img_h     = (float*)(ws + alloc(2048ull * 128 * 4));
  float* ph        = (float*)(ws + alloc(1000ull * 128 * 4));

  // transposes (976) + attrT (320) + gn tail (1) + poutT tail (1)
  tr3_k<<<1298, 256, 0, stream>>>(slim_w, slimT, img_w, imgwT, proto_w, protowT,
                                  attributes, poutT, gn_bf, poutT);

  // gn (125) + img_h full-K (16) + proto_redT full-K -> poutT rows 312..631 (24)
  mega_k<<<165, 256, 0, stream>>>(attributes, att_g, gn_bf,
                                  img_proto, slimT,
                                  image_feats, imgwT, img_h, poutT);

  // sim -> softmax -> propagate -> ph (fused; outs never materialized)
  attn4_k<<<63, 256, 0, stream>>>(gn_bf, poutT, slim_b, protowT, proto_b, ph);

  final_k<<<dim3(16, 16), 256, 0, stream>>>(img_h, ph, fc_w, fc_b, out);
}